// Round 1
// baseline (1839.203 us; speedup 1.0000x reference)
//
#include <hip/hip_runtime.h>

// Problem constants
#define NB 16
#define NT 24
#define NH 96
#define NW 96
#define NC 8     // input channels
#define NF 16    // ConvLSTM filters
#define NG 64    // 4*NF gate channels
#define HW (NH*NW)

// One ConvLSTM time step. Each thread computes one pixel: all 64 gate
// channels accumulate in registers; weights are read via uniform addresses
// (loop counters only) so they should lower to scalar loads.
__global__ __launch_bounds__(256) void convlstm_step(
    const float* __restrict__ x,     // [B,T,H,W,C]
    const float* __restrict__ wx,    // [3,3,NC,NG]
    const float* __restrict__ wh,    // [3,3,NF,NG]
    const float* __restrict__ bias,  // [NG]
    const float* __restrict__ h_in,  // [B,H,W,NF]
    float* __restrict__ h_out,       // [B,H,W,NF]
    float* __restrict__ c,           // [B,H,W,NF] (updated in place)
    int t)
{
    const int bpi = HW / 256;                 // 36 blocks per image
    const int b   = blockIdx.x / bpi;
    const int p   = (blockIdx.x % bpi) * 256 + threadIdx.x;  // pixel in image
    const int y   = p / NW;
    const int xw  = p % NW;

    float acc[NG];
    #pragma unroll
    for (int i = 0; i < NG; ++i) acc[i] = bias[i];

    const float* xb = x    + ((size_t)b * NT + t) * (size_t)HW * NC;
    const float* hb = h_in + (size_t)b * HW * NF;

    for (int tap = 0; tap < 9; ++tap) {       // not unrolled: keep I$ small
        const int dy = tap / 3 - 1;
        const int dx = tap % 3 - 1;
        const int yy = y + dy;
        const int xx = xw + dx;
        const bool ok = (yy >= 0) & (yy < NH) & (xx >= 0) & (xx < NW);
        const int yc = min(max(yy, 0), NH - 1);
        const int xc = min(max(xx, 0), NW - 1);
        const int np = yc * NW + xc;
        const float m = ok ? 1.0f : 0.0f;     // branch-free SAME padding

        // ---- x contribution: 8 input channels ----
        const float4* xp = (const float4*)(xb + (size_t)np * NC);
        float4 a0 = xp[0];
        float4 a1 = xp[1];
        float xs[NC] = {a0.x, a0.y, a0.z, a0.w, a1.x, a1.y, a1.z, a1.w};
        #pragma unroll
        for (int ci = 0; ci < NC; ++ci) xs[ci] *= m;

        const float* wxt = wx + tap * (NC * NG);
        #pragma unroll
        for (int ci = 0; ci < NC; ++ci) {
            const float xv = xs[ci];
            #pragma unroll
            for (int co = 0; co < NG; ++co)
                acc[co] = fmaf(xv, wxt[ci * NG + co], acc[co]);
        }

        // ---- h contribution: 16 recurrent channels ----
        const float4* hp = (const float4*)(hb + (size_t)np * NF);
        float4 h0 = hp[0], h1 = hp[1], h2 = hp[2], h3 = hp[3];
        float hs[NF] = {h0.x, h0.y, h0.z, h0.w, h1.x, h1.y, h1.z, h1.w,
                        h2.x, h2.y, h2.z, h2.w, h3.x, h3.y, h3.z, h3.w};
        #pragma unroll
        for (int ci = 0; ci < NF; ++ci) hs[ci] *= m;

        const float* wht = wh + tap * (NF * NG);
        #pragma unroll
        for (int ci = 0; ci < NF; ++ci) {
            const float hv = hs[ci];
            #pragma unroll
            for (int co = 0; co < NG; ++co)
                acc[co] = fmaf(hv, wht[ci * NG + co], acc[co]);
        }
    }

    // ---- gates + state update (i, f, c, o channel blocks) ----
    const size_t base = ((size_t)b * HW + p) * NF;
    const float4* cp = (const float4*)(c + base);
    float4 c0 = cp[0], c1 = cp[1], c2 = cp[2], c3 = cp[3];
    float cv[NF] = {c0.x, c0.y, c0.z, c0.w, c1.x, c1.y, c1.z, c1.w,
                    c2.x, c2.y, c2.z, c2.w, c3.x, c3.y, c3.z, c3.w};
    float hv[NF];
    #pragma unroll
    for (int k = 0; k < NF; ++k) {
        const float ig = fminf(fmaxf(0.2f * acc[k]          + 0.5f, 0.f), 1.f);
        const float fg = fminf(fmaxf(0.2f * acc[NF + k]     + 0.5f, 0.f), 1.f);
        const float cn = fg * cv[k] + ig * fmaxf(acc[2 * NF + k], 0.f);
        const float og = fminf(fmaxf(0.2f * acc[3 * NF + k] + 0.5f, 0.f), 1.f);
        cv[k] = cn;
        hv[k] = og * fmaxf(cn, 0.f);
    }
    float4* cw = (float4*)(c + base);
    cw[0] = make_float4(cv[0], cv[1], cv[2], cv[3]);
    cw[1] = make_float4(cv[4], cv[5], cv[6], cv[7]);
    cw[2] = make_float4(cv[8], cv[9], cv[10], cv[11]);
    cw[3] = make_float4(cv[12], cv[13], cv[14], cv[15]);
    float4* hw = (float4*)(h_out + base);
    hw[0] = make_float4(hv[0], hv[1], hv[2], hv[3]);
    hw[1] = make_float4(hv[4], hv[5], hv[6], hv[7]);
    hw[2] = make_float4(hv[8], hv[9], hv[10], hv[11]);
    hw[3] = make_float4(hv[12], hv[13], hv[14], hv[15]);
}

// Fused inference-BatchNorm + Dense(1): out = offset + sum_k h[k]*scale[k]
__global__ __launch_bounds__(256) void bn_dense(
    const float* __restrict__ h,      // [B,H,W,NF]
    const float* __restrict__ gamma,
    const float* __restrict__ beta,
    const float* __restrict__ mean,
    const float* __restrict__ var,
    const float* __restrict__ dw,     // [NF,1]
    const float* __restrict__ db,     // [1]
    float* __restrict__ out)          // [B,H,W,1]
{
    const int p = blockIdx.x * 256 + threadIdx.x;
    if (p >= NB * HW) return;

    float s = db[0];
    float dot = 0.f;
    const float4* hp = (const float4*)(h + (size_t)p * NF);
    float4 h0 = hp[0], h1 = hp[1], h2 = hp[2], h3 = hp[3];
    const float hvals[NF] = {h0.x, h0.y, h0.z, h0.w, h1.x, h1.y, h1.z, h1.w,
                             h2.x, h2.y, h2.z, h2.w, h3.x, h3.y, h3.z, h3.w};
    #pragma unroll
    for (int k = 0; k < NF; ++k) {
        const float inv = gamma[k] / sqrtf(var[k] + 1e-3f);
        s   += (beta[k] - mean[k] * inv) * dw[k];
        dot += hvals[k] * inv * dw[k];
    }
    out[p] = s + dot;
}

extern "C" void kernel_launch(void* const* d_in, const int* in_sizes, int n_in,
                              void* d_out, int out_size, void* d_ws, size_t ws_size,
                              hipStream_t stream) {
    const float* x     = (const float*)d_in[0];
    const float* wx    = (const float*)d_in[1];
    const float* wh    = (const float*)d_in[2];
    const float* bias  = (const float*)d_in[3];
    const float* gamma = (const float*)d_in[4];
    const float* beta  = (const float*)d_in[5];
    const float* mean  = (const float*)d_in[6];
    const float* var   = (const float*)d_in[7];
    const float* dw    = (const float*)d_in[8];
    const float* db    = (const float*)d_in[9];
    float* out = (float*)d_out;

    const size_t nh = (size_t)NB * HW * NF;   // 2,359,296 floats
    float* h0 = (float*)d_ws;
    float* h1 = h0 + nh;
    float* cc = h1 + nh;

    // h and c start at zero; h1 is fully written by step 0 before first read.
    hipMemsetAsync(h0, 0, nh * sizeof(float), stream);
    hipMemsetAsync(cc, 0, nh * sizeof(float), stream);

    const int blocks = NB * (HW / 256);       // 576
    for (int t = 0; t < NT; ++t) {
        const float* hin = (t & 1) ? h1 : h0;
        float*       hout = (t & 1) ? h0 : h1;
        convlstm_step<<<blocks, 256, 0, stream>>>(x, wx, wh, bias, hin, hout, cc, t);
    }
    // t=23 (odd) wrote h0
    bn_dense<<<blocks, 256, 0, stream>>>(h0, gamma, beta, mean, var, dw, db, out);
}

// Round 2
// 502.673 us; speedup vs baseline: 3.6588x; 3.6588x over previous
//
#include <hip/hip_runtime.h>

// Problem constants
#define NB 16
#define NT 24
#define NH 96
#define NW 96
#define NC 8     // input channels
#define NF 16    // ConvLSTM filters
#define NG 64    // 4*NF gate channels
#define HW (NH*NW)
#define KPAD 224 // 144 (h: 9 taps x 16) + 72 (x: 9 taps x 8) + 8 zero pad

typedef _Float16 f16x8 __attribute__((ext_vector_type(8)));
typedef float    f32x4 __attribute__((ext_vector_type(4)));

// ---------------------------------------------------------------------------
// Prep: pack both conv kernels, transposed + f16, into wT[n][k] (k-contiguous
// per gate so MFMA B-fragments are 16B ds_read_b128s).
//   k in [0,144):   wh, k = tap*16 + ci  -> wh flat idx = k*64 + n
//   k in [144,216): wx, k-144 = tap*8+ci -> wx flat idx = (k-144)*64 + n
//   k in [216,224): zero pad
// ---------------------------------------------------------------------------
__global__ __launch_bounds__(256) void prep_weights(
    const float* __restrict__ wx, const float* __restrict__ wh,
    _Float16* __restrict__ wT)
{
    const int idx = blockIdx.x * 256 + threadIdx.x;   // 64*224 = 14336 threads
    if (idx >= NG * KPAD) return;
    const int n = idx / KPAD;
    const int k = idx % KPAD;
    float v = 0.f;
    if (k < 144)      v = wh[k * NG + n];
    else if (k < 216) v = wx[(k - 144) * NG + n];
    wT[n * KPAD + k] = (_Float16)v;
}

// ---------------------------------------------------------------------------
// One ConvLSTM step, MFMA implicit-GEMM.
// Block: 16x16 pixel tile of one image, 256 threads (4 waves).
// Wave w: M-rows = tile rows ty in [4w, 4w+4), all 64 gates.
// ---------------------------------------------------------------------------
__global__ __launch_bounds__(256) void convlstm_step_mfma(
    const float* __restrict__ x,       // [B,T,H,W,C] fp32
    const _Float16* __restrict__ wT,   // [NG][KPAD]
    const float* __restrict__ bias,    // [NG]
    const _Float16* __restrict__ h_in, // [B,H,W,NF] f16
    _Float16* __restrict__ h_out,      // [B,H,W,NF] f16
    float* __restrict__ c,             // [B,H,W,NF] fp32, in place
    int t)
{
    __shared__ _Float16 hs[18 * 18 * NF];   // 20.7 KB halo'd h tile
    __shared__ _Float16 xs[18 * 18 * NC];   //  5.2 KB halo'd x tile (f16)
    __shared__ _Float16 ws[NG * KPAD];      // 28.7 KB weights

    const int tid  = threadIdx.x;
    const int wave = tid >> 6;
    const int lane = tid & 63;
    const int g    = lane >> 4;     // 0..3
    const int cl   = lane & 15;     // 0..15

    const int b    = blockIdx.x / 36;
    const int tile = blockIdx.x % 36;
    const int ty0  = (tile / 6) * 16;
    const int tx0  = (tile % 6) * 16;

    // ---- stage weights: 28672 B, 16B per thread-iter ----
    {
        const f16x8* src = (const f16x8*)wT;
        f16x8*       dst = (f16x8*)ws;
        #pragma unroll
        for (int i = 0; i < (NG * KPAD / 8) / 256; ++i)
            dst[i * 256 + tid] = src[i * 256 + tid];
    }

    // ---- stage h halo (18x18 pixels, 32B each), zero-fill outside image ----
    const _Float16* hb = h_in + (size_t)b * HW * NF;
    for (int i = tid; i < 324; i += 256) {
        const int gy = ty0 + (i / 18) - 1;
        const int gx = tx0 + (i % 18) - 1;
        f16x8 v0 = (f16x8)(_Float16)0.f, v1 = v0;
        if (gy >= 0 && gy < NH && gx >= 0 && gx < NW) {
            const f16x8* src = (const f16x8*)(hb + ((size_t)gy * NW + gx) * NF);
            v0 = src[0]; v1 = src[1];
        }
        *(f16x8*)&hs[i * NF]     = v0;
        *(f16x8*)&hs[i * NF + 8] = v1;
    }

    // ---- stage x halo with fp32->f16 convert ----
    const float* xb = x + ((size_t)b * NT + t) * (size_t)HW * NC;
    for (int i = tid; i < 324; i += 256) {
        const int gy = ty0 + (i / 18) - 1;
        const int gx = tx0 + (i % 18) - 1;
        f16x8 v = (f16x8)(_Float16)0.f;
        if (gy >= 0 && gy < NH && gx >= 0 && gx < NW) {
            const float4* src = (const float4*)(xb + ((size_t)gy * NW + gx) * NC);
            float4 a0 = src[0], a1 = src[1];
            v[0] = (_Float16)a0.x; v[1] = (_Float16)a0.y;
            v[2] = (_Float16)a0.z; v[3] = (_Float16)a0.w;
            v[4] = (_Float16)a1.x; v[5] = (_Float16)a1.y;
            v[6] = (_Float16)a1.z; v[7] = (_Float16)a1.w;
        }
        *(f16x8*)&xs[i * NC] = v;
    }

    __syncthreads();

    // ---- accumulators, init with bias (D frag: n = nf*16 + cl) ----
    f32x4 acc[4][4];
    #pragma unroll
    for (int nf = 0; nf < 4; ++nf) {
        const float bv = bias[nf * 16 + cl];
        #pragma unroll
        for (int mf = 0; mf < 4; ++mf) acc[mf][nf] = (f32x4)bv;
    }

    // ---- K loop: 7 chunks of 32 ----
    #pragma unroll
    for (int cc = 0; cc < 7; ++cc) {
        f16x8 bfr[4];
        #pragma unroll
        for (int nf = 0; nf < 4; ++nf)
            bfr[nf] = *(const f16x8*)&ws[(nf * 16 + cl) * KPAD + cc * 32 + g * 8];

        const int khat = cc * 32 + g * 8;   // per-lane (g varies)
        f16x8 afr[4];
        #pragma unroll
        for (int mf = 0; mf < 4; ++mf) {
            const int ty = (wave << 2) + mf;      // tile-local pixel row
            f16x8 a;
            if (khat < 144) {              // h region: tap = khat/16, ci0 = khat%16
                const int tap = khat >> 4;
                const int ci0 = khat & 15;
                a = *(const f16x8*)&hs[((ty + tap / 3) * 18 + cl + tap % 3) * NF + ci0];
            } else if (khat < 216) {       // x region: tap = (khat-144)/8
                const int tap = (khat - 144) >> 3;
                a = *(const f16x8*)&xs[((ty + tap / 3) * 18 + cl + tap % 3) * NC];
            } else {                       // zero pad
                a = (f16x8)(_Float16)0.f;
            }
            afr[mf] = a;
        }

        #pragma unroll
        for (int mf = 0; mf < 4; ++mf)
            #pragma unroll
            for (int nf = 0; nf < 4; ++nf)
                acc[mf][nf] = __builtin_amdgcn_mfma_f32_16x16x32_f16(
                    afr[mf], bfr[nf], acc[mf][nf], 0, 0, 0);
    }

    // ---- gates + state update ----
    // D frag: pixel (ty = 4*wave+mf, tx = 4*g+r), channel k = cl,
    // gates i/f/c/o = nf 0/1/2/3.
    #pragma unroll
    for (int mf = 0; mf < 4; ++mf) {
        const int gy = ty0 + (wave << 2) + mf;
        #pragma unroll
        for (int r = 0; r < 4; ++r) {
            const int gx = tx0 + (g << 2) + r;
            const size_t pix = (size_t)b * HW + (size_t)gy * NW + gx;
            const float zi = acc[mf][0][r];
            const float zf = acc[mf][1][r];
            const float zc = acc[mf][2][r];
            const float zo = acc[mf][3][r];
            const float ig = fminf(fmaxf(0.2f * zi + 0.5f, 0.f), 1.f);
            const float fg = fminf(fmaxf(0.2f * zf + 0.5f, 0.f), 1.f);
            const float og = fminf(fmaxf(0.2f * zo + 0.5f, 0.f), 1.f);
            const float cold = c[pix * NF + cl];
            const float cn = fg * cold + ig * fmaxf(zc, 0.f);
            c[pix * NF + cl] = cn;
            h_out[pix * NF + cl] = (_Float16)(og * fmaxf(cn, 0.f));
        }
    }
}

// ---------------------------------------------------------------------------
// Fused inference-BatchNorm + Dense(1) on f16 h.
// ---------------------------------------------------------------------------
__global__ __launch_bounds__(256) void bn_dense(
    const _Float16* __restrict__ h,   // [B,H,W,NF] f16
    const float* __restrict__ gamma,
    const float* __restrict__ beta,
    const float* __restrict__ mean,
    const float* __restrict__ var,
    const float* __restrict__ dw,     // [NF,1]
    const float* __restrict__ db,     // [1]
    float* __restrict__ out)          // [B,H,W,1]
{
    const int p = blockIdx.x * 256 + threadIdx.x;
    if (p >= NB * HW) return;

    const f16x8* hp = (const f16x8*)(h + (size_t)p * NF);
    f16x8 h0 = hp[0], h1 = hp[1];
    float s = db[0];
    float dot = 0.f;
    #pragma unroll
    for (int k = 0; k < NF; ++k) {
        const float inv = gamma[k] / sqrtf(var[k] + 1e-3f);
        const float hv = (k < 8) ? (float)h0[k] : (float)h1[k - 8];
        s   += (beta[k] - mean[k] * inv) * dw[k];
        dot += hv * inv * dw[k];
    }
    out[p] = s + dot;
}

extern "C" void kernel_launch(void* const* d_in, const int* in_sizes, int n_in,
                              void* d_out, int out_size, void* d_ws, size_t ws_size,
                              hipStream_t stream) {
    const float* x     = (const float*)d_in[0];
    const float* wx    = (const float*)d_in[1];
    const float* wh    = (const float*)d_in[2];
    const float* bias  = (const float*)d_in[3];
    const float* gamma = (const float*)d_in[4];
    const float* beta  = (const float*)d_in[5];
    const float* mean  = (const float*)d_in[6];
    const float* var   = (const float*)d_in[7];
    const float* dw    = (const float*)d_in[8];
    const float* db    = (const float*)d_in[9];
    float* out = (float*)d_out;

    // ws layout (all offsets 256B aligned):
    //   h0 f16: 2,359,296 els (4.72 MB)
    //   h1 f16: 4.72 MB
    //   c  f32: 9.44 MB
    //   wT f16: 64*224 els (28.7 KB)
    const size_t nh = (size_t)NB * HW * NF;
    _Float16* h0 = (_Float16*)d_ws;
    _Float16* h1 = h0 + nh;
    float*    cc = (float*)(h1 + nh);
    _Float16* wT = (_Float16*)(cc + nh);

    hipMemsetAsync(h0, 0, nh * sizeof(_Float16), stream);
    hipMemsetAsync(cc, 0, nh * sizeof(float), stream);

    prep_weights<<<(NG * KPAD + 255) / 256, 256, 0, stream>>>(wx, wh, wT);

    const int blocks = NB * 36;               // 576
    for (int t = 0; t < NT; ++t) {
        const _Float16* hin  = (t & 1) ? h1 : h0;
        _Float16*       hout = (t & 1) ? h0 : h1;
        convlstm_step_mfma<<<blocks, 256, 0, stream>>>(x, wT, bias, hin, hout, cc, t);
    }
    // t=23 (odd) wrote h0
    bn_dense<<<NB * HW / 256, 256, 0, stream>>>(h0, gamma, beta, mean, var, dw, db, out);
}